// Round 17
// baseline (55.843 us; speedup 1.0000x reference)
//
#include <hip/hip_runtime.h>
#include <math.h>
#include <stdint.h>

#define NB1    4096
#define NBTOT  8192
#define NFD    128
#define NSLICE 16                // column slices
#define ECOLS  512               // columns per block
#define BROWS  128
#define BCOLS  64
#define NTILES (ECOLS / BCOLS)   // 8
#define NSL    8                 // partial slices per class

typedef __attribute__((ext_vector_type(8))) _Float16 f16x8;
typedef __attribute__((ext_vector_type(4))) float f32x4;
typedef _Float16 f16;

// ---------------------------------------------------------------------------
// Kernel 1: row L2-normalize -> fp16 (validated R8: loss err ~0.015 << 0.0925)
// ---------------------------------------------------------------------------
__global__ void norm_k(const float* __restrict__ f1, const float* __restrict__ f2,
                       f16* __restrict__ nfh) {
    const int w = threadIdx.x >> 6, lane = threadIdx.x & 63;
    const int row = blockIdx.x * 4 + w;
    const float* src = (row < NB1) ? (f1 + (size_t)row * NFD)
                                   : (f2 + (size_t)(row - NB1) * NFD);
    const float2 v = *reinterpret_cast<const float2*>(src + 2 * lane);
    float s = v.x * v.x + v.y * v.y;
#pragma unroll
    for (int m = 32; m >= 1; m >>= 1) s += __shfl_xor(s, m, 64);
    const float inv = 1.0f / fmaxf(sqrtf(s), 1e-12f);
    const f16 h0 = (f16)(v.x * inv);
    const f16 h1 = (f16)(v.y * inv);
    const unsigned pack = (unsigned)__builtin_bit_cast(unsigned short, h0) |
                          ((unsigned)__builtin_bit_cast(unsigned short, h1) << 16);
    ((unsigned*)(nfh + (size_t)row * NFD))[lane] = pack;
}

// ---------------------------------------------------------------------------
// Kernel 2: ZERO-BARRIER direct-register sim-stats. nfh = 2MB -> fully
// L2-resident (fits one XCD's 4MB L2); LDS staging is pure overhead for
// L2-fit data (guide attn lesson #7). Each wave loads its B fragments
// DIRECTLY global->reg (L1/L2 hit), MFMAs, folds -- no LDS, no barriers in
// the loop; 3 desynced waves/SIMD hide L2 latency via TLP (m114), no
// lockstep. Grid (16 slices, 64 row-tiles) = 1024 blocks; 256 thr = 4 waves,
// 2x2 wave grid: rows 64*(w>>1) (fa=4), cols 32*(w&1) (fb=2). A-frags
// register-resident (R8-proven layout, absmax 0). One __syncthreads total.
// ---------------------------------------------------------------------------
__global__ __launch_bounds__(256, 3) void simstat_mfma(const f16* __restrict__ nfh,
                                                       float* __restrict__ posp,
                                                       float* __restrict__ sexpp) {
    __shared__ float scratch[256];

    const int e    = blockIdx.x;          // column slice 0..15
    const int rt   = blockIdx.y;
    const int row0 = rt * BROWS;
    const int col0e = e * ECOLS;
    const bool same = ((row0 >= NB1) == (e >= 8));
    const int p = e & 7;

    const int t    = threadIdx.x;
    const int w    = t >> 6;
    const int lane = t & 63;
    const int lr   = lane & 15;
    const int lg   = lane >> 4;
    const int rowbase = 64 * (w >> 1);    // 2 row-stripes of 64
    const int colbase = 32 * (w & 1);     // 2 col-stripes of 32

    // ---- A fragments -> registers (tile-invariant): 16 x 4 VGPR ----
    f16x8 ah[4][4];
#pragma unroll
    for (int ks = 0; ks < 4; ++ks)
#pragma unroll
        for (int fa = 0; fa < 4; ++fa) {
            const size_t off = (size_t)(row0 + rowbase + 16 * fa + lr) * NFD + 32 * ks + 8 * lg;
            ah[ks][fa] = *reinterpret_cast<const f16x8*>(nfh + off);
        }

    float stat[4][4];
#pragma unroll
    for (int fa = 0; fa < 4; ++fa)
#pragma unroll
        for (int r = 0; r < 4; ++r) stat[fa][r] = same ? -3.0e38f : 0.0f;
    const float K2 = 1.44269504089f / 0.07f;   // log2(e)/tau
    const float invtau = 1.0f / 0.07f;

    // per-lane B offset within a tile: col (colbase+16*fb+lr), k (32*ks+8*lg)
    size_t boff[4][2];
#pragma unroll
    for (int ks = 0; ks < 4; ++ks)
#pragma unroll
        for (int fb = 0; fb < 2; ++fb)
            boff[ks][fb] = (size_t)(colbase + 16 * fb + lr) * NFD + 32 * ks + 8 * lg;

#pragma unroll 1
    for (int tile = 0; tile < NTILES; ++tile) {
        const f16* bbase = nfh + (size_t)(col0e + tile * BCOLS) * NFD;

        // direct global->reg B fragments (L1/L2 hit; compiler pipelines)
        f16x8 b[4][2];
#pragma unroll
        for (int ks = 0; ks < 4; ++ks)
#pragma unroll
            for (int fb = 0; fb < 2; ++fb)
                b[ks][fb] = *reinterpret_cast<const f16x8*>(bbase + boff[ks][fb]);

        f32x4 acc[4][2];
#pragma unroll
        for (int fa = 0; fa < 4; ++fa)
#pragma unroll
            for (int fb = 0; fb < 2; ++fb) {
                f32x4 z = {0.0f, 0.0f, 0.0f, 0.0f};
                acc[fa][fb] = z;
            }

        __builtin_amdgcn_s_setprio(1);
#pragma unroll
        for (int ks = 0; ks < 4; ++ks)
#pragma unroll
            for (int fb = 0; fb < 2; ++fb)
#pragma unroll
                for (int fa = 0; fa < 4; ++fa)
                    acc[fa][fb] = __builtin_amdgcn_mfma_f32_16x16x32_f16(ah[ks][fa], b[ks][fb], acc[fa][fb], 0, 0, 0);
        __builtin_amdgcn_s_setprio(0);

        // fold acc into stat; C/D: col=lane&15, row=4*lg+reg (m89-verified)
        if (same) {
            const int col0 = col0e + tile * BCOLS;
#pragma unroll
            for (int fa = 0; fa < 4; ++fa)
#pragma unroll
                for (int fb = 0; fb < 2; ++fb)
#pragma unroll
                    for (int r = 0; r < 4; ++r) {
                        const int grow = row0 + rowbase + 16 * fa + 4 * lg + r;
                        const int gcol = col0 + colbase + 16 * fb + lr;
                        stat[fa][r] = (grow == gcol) ? stat[fa][r]
                                                     : fmaxf(stat[fa][r], acc[fa][fb][r]);
                    }
        } else {
#pragma unroll
            for (int fa = 0; fa < 4; ++fa)
#pragma unroll
                for (int fb = 0; fb < 2; ++fb)
#pragma unroll
                    for (int r = 0; r < 4; ++r)
                        stat[fa][r] += exp2f(acc[fa][fb][r] * K2);
        }
        // NO barrier -- waves free-run
    }

    // reduce over the 16 cols held across lr (lane bits 0..3)
#pragma unroll
    for (int m = 1; m <= 8; m <<= 1) {
#pragma unroll
        for (int fa = 0; fa < 4; ++fa)
#pragma unroll
            for (int r = 0; r < 4; ++r) {
                const float o = __shfl_xor(stat[fa][r], m, 64);
                stat[fa][r] = same ? fmaxf(stat[fa][r], o) : (stat[fa][r] + o);
            }
    }

    // combine the two col-stripe waves per row (the ONLY barrier)
    if (lr == 0) {
#pragma unroll
        for (int fa = 0; fa < 4; ++fa)
#pragma unroll
            for (int r = 0; r < 4; ++r) {
                const int rl = rowbase + 16 * fa + 4 * lg + r;
                scratch[(w & 1) * 128 + rl] = stat[fa][r];
            }
    }
    __syncthreads();
    if (t < 128) {
        const float v0 = scratch[t];
        const float v1 = scratch[128 + t];
        const float v = same ? fmaxf(v0, v1) * invtau : (v0 + v1);
        (same ? posp : sexpp)[(size_t)p * NBTOT + row0 + t] = v;
    }
}

// ---------------------------------------------------------------------------
// Kernel 3a: per-row loss partials, 32 blocks. loss_i = log1p(S*exp(-pos))
// ---------------------------------------------------------------------------
__global__ void loss_part(const float* __restrict__ posp, const float* __restrict__ sexpp,
                          float* __restrict__ partial) {
    const int i = blockIdx.x * 256 + threadIdx.x;
    float pv = -3.0e38f, se = 0.0f;
#pragma unroll
    for (int s = 0; s < NSL; ++s) {
        pv = fmaxf(pv, posp[(size_t)s * NBTOT + i]);
        se += sexpp[(size_t)s * NBTOT + i];
    }
    float l = log1pf(se * __expf(-pv));
#pragma unroll
    for (int m = 32; m >= 1; m >>= 1) l += __shfl_xor(l, m, 64);
    __shared__ float part[4];
    if ((threadIdx.x & 63) == 0) part[threadIdx.x >> 6] = l;
    __syncthreads();
    if (threadIdx.x == 0)
        partial[blockIdx.x] = part[0] + part[1] + part[2] + part[3];
}

// Kernel 3b: final combine (1 wave).
__global__ void loss_final(const float* __restrict__ partial, float* __restrict__ out) {
    const int t = threadIdx.x;
    float s = (t < 32) ? partial[t] : 0.0f;
#pragma unroll
    for (int m = 32; m >= 1; m >>= 1) s += __shfl_xor(s, m, 64);
    if (t == 0) out[0] = s / (float)NBTOT;
}

// ---------------------------------------------------------------------------
extern "C" void kernel_launch(void* const* d_in, const int* in_sizes, int n_in,
                              void* d_out, int out_size, void* d_ws, size_t ws_size,
                              hipStream_t stream) {
    const float* f1 = (const float*)d_in[0];
    const float* f2 = (const float*)d_in[1];

    f16*   nfh     = (f16*)d_ws;                          // 2 MB
    float* posp    = (float*)(nfh + (size_t)NBTOT * NFD); // 8*8192 f32
    float* sexpp   = posp + (size_t)NSL * NBTOT;          // 8*8192 f32
    float* partial = sexpp + (size_t)NSL * NBTOT;         // 32 f32

    norm_k<<<NBTOT / 4, 256, 0, stream>>>(f1, f2, nfh);
    simstat_mfma<<<dim3(NSLICE, 64), 256, 0, stream>>>(nfh, posp, sexpp);
    loss_part<<<NBTOT / 256, 256, 0, stream>>>(posp, sexpp, partial);
    loss_final<<<1, 64, 0, stream>>>(partial, (float*)d_out);
}

// Round 18
// 45.745 us; speedup vs baseline: 1.2207x; 1.2207x over previous
//
#include <hip/hip_runtime.h>
#include <math.h>
#include <stdint.h>

#define NB1    4096
#define NBTOT  8192
#define NFD    128
#define NSLICE 16                // column slices
#define ECOLS  512               // columns per block
#define BROWS  128
#define BCOLS  64
#define NTILES (ECOLS / BCOLS)   // 8
#define NSL    8                 // partial slices per class

typedef __attribute__((ext_vector_type(8))) _Float16 f16x8;
typedef __attribute__((ext_vector_type(4))) float f32x4;
typedef _Float16 f16;

// async 16B global->LDS; lds base wave-uniform, HW adds lane*16
__device__ __forceinline__ void gl16(const f16* g, char* l) {
    __builtin_amdgcn_global_load_lds(
        (const __attribute__((address_space(1))) unsigned int*)g,
        (__attribute__((address_space(3))) unsigned int*)l,
        16, 0, 0);
}

// ---------------------------------------------------------------------------
// Kernel 1: row L2-normalize -> fp16 (validated: loss err ~0.015 << 0.0925)
// ---------------------------------------------------------------------------
__global__ void norm_k(const float* __restrict__ f1, const float* __restrict__ f2,
                       f16* __restrict__ nfh) {
    const int w = threadIdx.x >> 6, lane = threadIdx.x & 63;
    const int row = blockIdx.x * 4 + w;
    const float* src = (row < NB1) ? (f1 + (size_t)row * NFD)
                                   : (f2 + (size_t)(row - NB1) * NFD);
    const float2 v = *reinterpret_cast<const float2*>(src + 2 * lane);
    float s = v.x * v.x + v.y * v.y;
#pragma unroll
    for (int m = 32; m >= 1; m >>= 1) s += __shfl_xor(s, m, 64);
    const float inv = 1.0f / fmaxf(sqrtf(s), 1e-12f);
    const f16 h0 = (f16)(v.x * inv);
    const f16 h1 = (f16)(v.y * inv);
    const unsigned pack = (unsigned)__builtin_bit_cast(unsigned short, h0) |
                          ((unsigned)__builtin_bit_cast(unsigned short, h1) << 16);
    ((unsigned*)(nfh + (size_t)row * NFD))[lane] = pack;
}

// ---------------------------------------------------------------------------
// Kernel 2: fp16 MFMA sim-stats — the measured-best R8 structure (40.4 us,
// absmax 0.0). Grid (16 col-slices, 64 row-tiles) = 1024 blocks; 256 thr =
// 4 waves, 2x2 wave grid: wave w -> rows 64*(w>>1) (fa=4), cols 32*(w&1)
// (fb=2) -> 0.25 ds_read_b128 per MFMA. A-frags register-resident (64 VGPR,
// tile-invariant). LDS = B dbuf 2x16KB; 4-bit XOR swizzle via pre-swizzled
// global_load_lds source (0 bank conflicts measured). launch_bounds (256,3)
// -> 84 VGPR alloc (measured), no spill. Per tile: issue next stage early,
// ks-loop {2 ds_read -> setprio(1) 8 MFMA setprio(0)}, fold, __syncthreads.
// Ledger: one-barrier / triangle / counted-vmcnt / zero-barrier / 4-wave
// bound all regressed vs this (R11-R17) — do not perturb.
// ---------------------------------------------------------------------------
__global__ __launch_bounds__(256, 3) void simstat_mfma(const f16* __restrict__ nfh,
                                                       float* __restrict__ posp,
                                                       float* __restrict__ sexpp) {
    extern __shared__ __align__(16) char smem[];   // 32768 = 2 x 16KB

    const int e    = blockIdx.x;          // column slice 0..15
    const int rt   = blockIdx.y;
    const int row0 = rt * BROWS;
    const int col0e = e * ECOLS;
    const bool same = ((row0 >= NB1) == (e >= 8));
    const int p = e & 7;

    const int t    = threadIdx.x;
    const int w    = t >> 6;
    const int lane = t & 63;
    const int lr   = lane & 15;
    const int lg   = lane >> 4;
    const int rowbase = 64 * (w >> 1);    // 2 row-stripes of 64
    const int colbase = 32 * (w & 1);     // 2 col-stripes of 32

    // ---- stage mapping (loop-invariant): 4 waves x 4KB = 16KB tile ----
    int goffs[4], dbase[4];
#pragma unroll
    for (int i = 0; i < 4; ++i) {
        const int base = w * 4096 + i * 1024;
        const int d    = base + lane * 16;
        const int sr   = d >> 8;            // dest row 0..63
        const int slot = (d >> 4) & 15;
        const int kc   = slot ^ (sr & 15);  // source k-chunk (involution)
        goffs[i] = sr * NFD + kc * 8;
        dbase[i] = base;
    }
    // read offsets (row&15 == lr since colbase,16*fb are multiples of 16)
    int rbo[2], koff[4];
#pragma unroll
    for (int fb = 0; fb < 2; ++fb) rbo[fb] = (colbase + 16 * fb + lr) * 256;
#pragma unroll
    for (int ks = 0; ks < 4; ++ks) koff[ks] = (((ks << 2) + lg) ^ lr) << 4;

    // ---- stage B tile 0 (async) ----
    {
        const f16* g0 = nfh + (size_t)col0e * NFD;
#pragma unroll
        for (int i = 0; i < 4; ++i) gl16(g0 + goffs[i], smem + dbase[i]);
    }

    // ---- A fragments -> registers (tile-invariant): 16 x 4 VGPR ----
    f16x8 ah[4][4];
#pragma unroll
    for (int ks = 0; ks < 4; ++ks)
#pragma unroll
        for (int fa = 0; fa < 4; ++fa) {
            const size_t off = (size_t)(row0 + rowbase + 16 * fa + lr) * NFD + 32 * ks + 8 * lg;
            ah[ks][fa] = *reinterpret_cast<const f16x8*>(nfh + off);
        }

    __syncthreads();   // tile0 + A loads complete

    float stat[4][4];
#pragma unroll
    for (int fa = 0; fa < 4; ++fa)
#pragma unroll
        for (int r = 0; r < 4; ++r) stat[fa][r] = same ? -3.0e38f : 0.0f;
    const float K2 = 1.44269504089f / 0.07f;   // log2(e)/tau
    const float invtau = 1.0f / 0.07f;

#pragma unroll 1
    for (int tile = 0; tile < NTILES; ++tile) {
        const char* bufB = smem + (tile & 1) * 16384;

        // issue next-tile stage early (lands during compute, drained at barrier)
        if (tile + 1 < NTILES) {
            char* nb = smem + ((tile + 1) & 1) * 16384;
            const f16* gn = nfh + (size_t)(col0e + (tile + 1) * BCOLS) * NFD;
#pragma unroll
            for (int i = 0; i < 4; ++i) gl16(gn + goffs[i], nb + dbase[i]);
        }

        f32x4 acc[4][2];
#pragma unroll
        for (int fa = 0; fa < 4; ++fa)
#pragma unroll
            for (int fb = 0; fb < 2; ++fb) {
                f32x4 z = {0.0f, 0.0f, 0.0f, 0.0f};
                acc[fa][fb] = z;
            }

#pragma unroll
        for (int ks = 0; ks < 4; ++ks) {
            f16x8 b[2];
#pragma unroll
            for (int fb = 0; fb < 2; ++fb)
                b[fb] = *(const f16x8*)(bufB + rbo[fb] + koff[ks]);
            __builtin_amdgcn_s_setprio(1);
#pragma unroll
            for (int fb = 0; fb < 2; ++fb)
#pragma unroll
                for (int fa = 0; fa < 4; ++fa)
                    acc[fa][fb] = __builtin_amdgcn_mfma_f32_16x16x32_f16(ah[ks][fa], b[fb], acc[fa][fb], 0, 0, 0);
            __builtin_amdgcn_s_setprio(0);
        }

        // fold acc into stat; C/D: col=lane&15, row=4*lg+reg (m89-verified)
        if (same) {
            const int col0 = col0e + tile * BCOLS;
#pragma unroll
            for (int fa = 0; fa < 4; ++fa)
#pragma unroll
                for (int fb = 0; fb < 2; ++fb)
#pragma unroll
                    for (int r = 0; r < 4; ++r) {
                        const int grow = row0 + rowbase + 16 * fa + 4 * lg + r;
                        const int gcol = col0 + colbase + 16 * fb + lr;
                        stat[fa][r] = (grow == gcol) ? stat[fa][r]
                                                     : fmaxf(stat[fa][r], acc[fa][fb][r]);
                    }
        } else {
#pragma unroll
            for (int fa = 0; fa < 4; ++fa)
#pragma unroll
                for (int fb = 0; fb < 2; ++fb)
#pragma unroll
                    for (int r = 0; r < 4; ++r)
                        stat[fa][r] += exp2f(acc[fa][fb][r] * K2);
        }

        __syncthreads();
    }

    // reduce over the 16 cols held across lr (lane bits 0..3)
#pragma unroll
    for (int m = 1; m <= 8; m <<= 1) {
#pragma unroll
        for (int fa = 0; fa < 4; ++fa)
#pragma unroll
            for (int r = 0; r < 4; ++r) {
                const float o = __shfl_xor(stat[fa][r], m, 64);
                stat[fa][r] = same ? fmaxf(stat[fa][r], o) : (stat[fa][r] + o);
            }
    }

    // combine the two col-stripe waves per row via LDS scratch
    float* scratch = (float*)smem;
    if (lr == 0) {
#pragma unroll
        for (int fa = 0; fa < 4; ++fa)
#pragma unroll
            for (int r = 0; r < 4; ++r) {
                const int rl = rowbase + 16 * fa + 4 * lg + r;
                scratch[(w & 1) * 128 + rl] = stat[fa][r];
            }
    }
    __syncthreads();
    if (t < 128) {
        const float v0 = scratch[t];
        const float v1 = scratch[128 + t];
        const float v = same ? fmaxf(v0, v1) * invtau : (v0 + v1);
        (same ? posp : sexpp)[(size_t)p * NBTOT + row0 + t] = v;
    }
}

// ---------------------------------------------------------------------------
// Kernel 3a: per-row loss partials, 32 blocks. loss_i = log1p(S*exp(-pos))
// ---------------------------------------------------------------------------
__global__ void loss_part(const float* __restrict__ posp, const float* __restrict__ sexpp,
                          float* __restrict__ partial) {
    const int i = blockIdx.x * 256 + threadIdx.x;
    float pv = -3.0e38f, se = 0.0f;
#pragma unroll
    for (int s = 0; s < NSL; ++s) {
        pv = fmaxf(pv, posp[(size_t)s * NBTOT + i]);
        se += sexpp[(size_t)s * NBTOT + i];
    }
    float l = log1pf(se * __expf(-pv));
#pragma unroll
    for (int m = 32; m >= 1; m >>= 1) l += __shfl_xor(l, m, 64);
    __shared__ float part[4];
    if ((threadIdx.x & 63) == 0) part[threadIdx.x >> 6] = l;
    __syncthreads();
    if (threadIdx.x == 0)
        partial[blockIdx.x] = part[0] + part[1] + part[2] + part[3];
}

// Kernel 3b: final combine (1 wave).
__global__ void loss_final(const float* __restrict__ partial, float* __restrict__ out) {
    const int t = threadIdx.x;
    float s = (t < 32) ? partial[t] : 0.0f;
#pragma unroll
    for (int m = 32; m >= 1; m >>= 1) s += __shfl_xor(s, m, 64);
    if (t == 0) out[0] = s / (float)NBTOT;
}

// ---------------------------------------------------------------------------
extern "C" void kernel_launch(void* const* d_in, const int* in_sizes, int n_in,
                              void* d_out, int out_size, void* d_ws, size_t ws_size,
                              hipStream_t stream) {
    const float* f1 = (const float*)d_in[0];
    const float* f2 = (const float*)d_in[1];

    f16*   nfh     = (f16*)d_ws;                          // 2 MB
    float* posp    = (float*)(nfh + (size_t)NBTOT * NFD); // 8*8192 f32
    float* sexpp   = posp + (size_t)NSL * NBTOT;          // 8*8192 f32
    float* partial = sexpp + (size_t)NSL * NBTOT;         // 32 f32

    (void)hipFuncSetAttribute(reinterpret_cast<const void*>(simstat_mfma),
                              hipFuncAttributeMaxDynamicSharedMemorySize, 32768);

    norm_k<<<NBTOT / 4, 256, 0, stream>>>(f1, f2, nfh);
    simstat_mfma<<<dim3(NSLICE, 64), 256, 32768, stream>>>(nfh, posp, sexpp);
    loss_part<<<NBTOT / 256, 256, 0, stream>>>(posp, sexpp, partial);
    loss_final<<<1, 64, 0, stream>>>(partial, (float*)d_out);
}